// Round 6
// baseline (508.005 us; speedup 1.0000x reference)
//
#include <hip/hip_runtime.h>
#include <stdint.h>

// ---------- problem constants ----------
#define B_DIM 2
#define T_DIM 4096
#define C_DIM 512
#define H_DIM 8
#define D_DIM 64
#define M_DIM (B_DIM * T_DIM)   // 8192

typedef __attribute__((ext_vector_type(8))) short bf16x8;   // MFMA A/B frag (8 bf16)
typedef __attribute__((ext_vector_type(4))) float f32x4;    // MFMA C/D frag
typedef __attribute__((ext_vector_type(4))) short short4v;  // 8B vector

__device__ inline unsigned short f2bf(float f) {
    union { float f; uint32_t u; } v; v.f = f;
    uint32_t r = v.u + 0x7fffu + ((v.u >> 16) & 1u);   // RNE
    return (unsigned short)(r >> 16);
}

__device__ inline uint32_t packbf(float a, float b) {
    return (uint32_t)f2bf(a) | ((uint32_t)f2bf(b) << 16);
}

// ---------- f32 -> bf16 conversion (x) ----------
__global__ __launch_bounds__(256) void cvt_kernel(const float* __restrict__ in,
                                                  unsigned short* __restrict__ out, int n) {
    int i = (blockIdx.x * 256 + threadIdx.x) * 4;
    if (i >= n) return;
    float4 v = *(const float4*)(in + i);
    short4v o;
    o[0] = (short)f2bf(v.x);
    o[1] = (short)f2bf(v.y);
    o[2] = (short)f2bf(v.z);
    o[3] = (short)f2bf(v.w);
    *(short4v*)(out + i) = o;
}

// ---------- batched f32 -> bf16 for the 4 weight matrices ----------
// 256 blocks per weight (512*512/(4*256) = 256); out contiguous [4][512][512].
__global__ __launch_bounds__(256) void cvt_w_kernel(const float* __restrict__ Wq,
                                                    const float* __restrict__ Wk,
                                                    const float* __restrict__ Wv,
                                                    const float* __restrict__ Wo,
                                                    unsigned short* __restrict__ out) {
    const int widx = blockIdx.x >> 8;
    const float* src = (widx == 0) ? Wq : (widx == 1) ? Wk : (widx == 2) ? Wv : Wo;
    const int i = ((blockIdx.x & 255) * 256 + threadIdx.x) * 4;
    float4 v = *(const float4*)(src + i);
    short4v o;
    o[0] = (short)f2bf(v.x);
    o[1] = (short)f2bf(v.y);
    o[2] = (short)f2bf(v.z);
    o[3] = (short)f2bf(v.w);
    *(short4v*)(out + (size_t)widx * C_DIM * C_DIM + i) = o;
}

// ---------- fused Q/K/V GEMM: z = blockIdx.z selects weight & output ----------
// Y[m][n] = sum_k A[m][k] * W[n][k]. 128x64 block tile, wave computes 32x64.
// z=0 -> Q head-split [B][H][T][D]; z=1 -> K same; z=2 -> V transposed+permuted
// [B][H][D][T'] where within each 32-col group column kv sits at
// p = ((kv>>2)&3)*8 + ((kv>>4)&1)*4 + (kv&3) so the attn PV A-frag is one 16B load.
__global__ __launch_bounds__(256) void gemm_qkv(const unsigned short* __restrict__ A,
                                                const unsigned short* __restrict__ Wb,
                                                unsigned short* __restrict__ Qh,
                                                unsigned short* __restrict__ Kh,
                                                unsigned short* __restrict__ Vt) {
    const int wave = threadIdx.x >> 6;
    const int lane = threadIdx.x & 63;
    const int g    = lane >> 4;
    const int lr   = lane & 15;
    const int row0 = blockIdx.x * 128 + wave * 32;
    const int col0 = blockIdx.y * 64;
    const int z    = blockIdx.z;
    const unsigned short* W = Wb + (size_t)z * C_DIM * C_DIM;

    f32x4 acc[2][4];
#pragma unroll
    for (int r = 0; r < 2; ++r)
#pragma unroll
        for (int i = 0; i < 4; ++i) acc[r][i] = (f32x4){0.f, 0.f, 0.f, 0.f};

    const unsigned short* Arow0 = A + (size_t)(row0 + lr) * C_DIM;
    const unsigned short* Arow1 = A + (size_t)(row0 + 16 + lr) * C_DIM;
#pragma unroll 4
    for (int kk = 0; kk < C_DIM; kk += 32) {
        bf16x8 a0 = *(const bf16x8*)(Arow0 + kk + g * 8);
        bf16x8 a1 = *(const bf16x8*)(Arow1 + kk + g * 8);
#pragma unroll
        for (int nt = 0; nt < 4; ++nt) {
            const unsigned short* Wrow = W + (size_t)(col0 + nt * 16 + lr) * C_DIM;
            bf16x8 b = *(const bf16x8*)(Wrow + kk + g * 8);
            acc[0][nt] = __builtin_amdgcn_mfma_f32_16x16x32_bf16(a0, b, acc[0][nt], 0, 0, 0);
            acc[1][nt] = __builtin_amdgcn_mfma_f32_16x16x32_bf16(a1, b, acc[1][nt], 0, 0, 0);
        }
    }

    unsigned short* Oqk = (z == 0) ? Qh : Kh;
#pragma unroll
    for (int ar = 0; ar < 2; ++ar) {
        const int rowb = row0 + ar * 16;
#pragma unroll
        for (int nt = 0; nt < 4; ++nt) {
            const int n = col0 + nt * 16 + lr;
            const int h = n >> 6, d = n & 63;
            if (z < 2) {
#pragma unroll
                for (int j = 0; j < 4; ++j) {
                    int m = rowb + g * 4 + j;
                    int b = m >> 12, t = m & (T_DIM - 1);
                    Oqk[((size_t)(b * H_DIM + h) * T_DIM + t) * D_DIM + d] = f2bf(acc[ar][nt][j]);
                }
            } else {
                int m = rowb + g * 4;
                int b = m >> 12, t = m & (T_DIM - 1);
                int tp = (t & ~31) | (((t >> 2) & 3) << 3) | (((t >> 4) & 1) << 2);
                short4v pack;
#pragma unroll
                for (int j = 0; j < 4; ++j) pack[j] = (short)f2bf(acc[ar][nt][j]);
                *(short4v*)(Vt + ((size_t)(b * H_DIM + h) * D_DIM + d) * T_DIM + tp) = pack;
            }
        }
    }
}

// ---------- output GEMM (f32 out) ----------
__global__ __launch_bounds__(256) void gemm_out(const unsigned short* __restrict__ A,
                                                const unsigned short* __restrict__ W,
                                                float* __restrict__ O) {
    const int wave = threadIdx.x >> 6;
    const int lane = threadIdx.x & 63;
    const int g    = lane >> 4;
    const int lr   = lane & 15;
    const int row0 = blockIdx.x * 128 + wave * 32;
    const int col0 = blockIdx.y * 64;

    f32x4 acc[2][4];
#pragma unroll
    for (int r = 0; r < 2; ++r)
#pragma unroll
        for (int i = 0; i < 4; ++i) acc[r][i] = (f32x4){0.f, 0.f, 0.f, 0.f};

    const unsigned short* Arow0 = A + (size_t)(row0 + lr) * C_DIM;
    const unsigned short* Arow1 = A + (size_t)(row0 + 16 + lr) * C_DIM;
#pragma unroll 4
    for (int kk = 0; kk < C_DIM; kk += 32) {
        bf16x8 a0 = *(const bf16x8*)(Arow0 + kk + g * 8);
        bf16x8 a1 = *(const bf16x8*)(Arow1 + kk + g * 8);
#pragma unroll
        for (int nt = 0; nt < 4; ++nt) {
            const unsigned short* Wrow = W + (size_t)(col0 + nt * 16 + lr) * C_DIM;
            bf16x8 b = *(const bf16x8*)(Wrow + kk + g * 8);
            acc[0][nt] = __builtin_amdgcn_mfma_f32_16x16x32_bf16(a0, b, acc[0][nt], 0, 0, 0);
            acc[1][nt] = __builtin_amdgcn_mfma_f32_16x16x32_bf16(a1, b, acc[1][nt], 0, 0, 0);
        }
    }

#pragma unroll
    for (int ar = 0; ar < 2; ++ar) {
        const int rowb = row0 + ar * 16;
#pragma unroll
        for (int nt = 0; nt < 4; ++nt) {
            const int n = col0 + nt * 16 + lr;
#pragma unroll
            for (int j = 0; j < 4; ++j) {
                int m = rowb + g * 4 + j;
                O[(size_t)m * C_DIM + n] = acc[ar][nt][j];
            }
        }
    }
}

// ---------- causal flash attention, 4-way parity-split uniform waves ----------
// Q,K: [B*H][T][D] bf16.  Vt: [B*H][D][T'] bf16 (kv-permuted).  attn out: [B*T][C] bf16.
// Block = 256 threads = 4 waves; block owns tile pair (qb=ord, 127-ord) of one head.
// Wave w processes kv-blocks kv0 = w*64 + 256k across BOTH tiles -> every wave
// ~16 iterations regardless of ord. Grid 1024 blocks = 4/CU = 4 waves/SIMD.
// Partials merged serially through one reused LDS buffer (3 publish/merge steps).
// All softmax arithmetic finite (sentinel/mask -1e30): empty parity -> weight 0.
__global__ __launch_bounds__(256, 4) void attn_kernel(const unsigned short* __restrict__ Qh,
                                                      const unsigned short* __restrict__ Kh,
                                                      const unsigned short* __restrict__ Vt,
                                                      unsigned short* __restrict__ attn) {
    const int wave = threadIdx.x >> 6;   // kv parity 0..3
    const int lane = threadIdx.x & 63;
    const int g    = lane >> 4;
    const int lr   = lane & 15;
    const int bh   = blockIdx.x & 15;
    const int ord  = blockIdx.x >> 4;    // 0..63

    const unsigned short* Qp = Qh + (size_t)bh * T_DIM * D_DIM;
    const unsigned short* Kp = Kh + (size_t)bh * T_DIM * D_DIM;
    const unsigned short* Vp = Vt + (size_t)bh * D_DIM * T_DIM;

    const float KC = 0.125f * 1.44269504f;   // scale * log2(e)

    __shared__ float lds_o[2][2][64][17];    // [tile][h][lane][16 elems + pad]
    __shared__ float lds_m[2][2][16];
    __shared__ float lds_l[2][2][16];

    f32x4 oacc[2][2][4];
    float mR[2][2], lR[2][2];

#pragma unroll
    for (int t = 0; t < 2; ++t) {
        const int qb = (t == 0) ? ord : (127 - ord);
        const int qw = qb * 32;
        const int kvend = qw + 32;

        bf16x8 qf[2][2];
#pragma unroll
        for (int h = 0; h < 2; ++h)
#pragma unroll
            for (int dh = 0; dh < 2; ++dh)
                qf[h][dh] = *(const bf16x8*)(Qp + (size_t)(qw + h * 16 + lr) * D_DIM + dh * 32 + g * 8);

#pragma unroll
        for (int h = 0; h < 2; ++h) {
#pragma unroll
            for (int d0 = 0; d0 < 4; ++d0) oacc[t][h][d0] = (f32x4){0.f, 0.f, 0.f, 0.f};
            mR[t][h] = -1e30f;
            lR[t][h] = 0.f;
        }

        const int kvstart = wave * 64;
        // prologue K frags (rows kvstart..kvstart+63 always < T_DIM)
        bf16x8 kc8[4][2];
#pragma unroll
        for (int i = 0; i < 4; ++i)
#pragma unroll
            for (int dh = 0; dh < 2; ++dh)
                kc8[i][dh] = *(const bf16x8*)(Kp + (size_t)(kvstart + i * 16 + lr) * D_DIM + dh * 32 + g * 8);

        for (int kv0 = kvstart; kv0 < kvend; kv0 += 256) {
            // ---- prefetch next-parity-iteration K (wrap harmlessly) ----
            const int kvn = (kv0 + 256 < kvend) ? kv0 + 256 : kvstart;
            bf16x8 kn8[4][2];
#pragma unroll
            for (int i = 0; i < 4; ++i)
#pragma unroll
                for (int dh = 0; dh < 2; ++dh)
                    kn8[i][dh] = *(const bf16x8*)(Kp + (size_t)(kvn + i * 16 + lr) * D_DIM + dh * 32 + g * 8);

            // ---- V loads (permuted layout: one 16B load per PV A-frag) ----
            bf16x8 vf[2][4];
#pragma unroll
            for (int kh = 0; kh < 2; ++kh)
#pragma unroll
                for (int d0 = 0; d0 < 4; ++d0)
                    vf[kh][d0] = *(const bf16x8*)(Vp + (size_t)(d0 * 16 + lr) * T_DIM + kv0 + kh * 32 + g * 8);

            // ---- QK^T: both q-halves share every K frag ----
            f32x4 s[2][4];
#pragma unroll
            for (int h = 0; h < 2; ++h)
#pragma unroll
                for (int i = 0; i < 4; ++i) s[h][i] = (f32x4){0.f, 0.f, 0.f, 0.f};
#pragma unroll
            for (int i = 0; i < 4; ++i) {
                s[0][i] = __builtin_amdgcn_mfma_f32_16x16x32_bf16(kc8[i][0], qf[0][0], s[0][i], 0, 0, 0);
                s[0][i] = __builtin_amdgcn_mfma_f32_16x16x32_bf16(kc8[i][1], qf[0][1], s[0][i], 0, 0, 0);
                s[1][i] = __builtin_amdgcn_mfma_f32_16x16x32_bf16(kc8[i][0], qf[1][0], s[1][i], 0, 0, 0);
                s[1][i] = __builtin_amdgcn_mfma_f32_16x16x32_bf16(kc8[i][1], qf[1][1], s[1][i], 0, 0, 0);
            }

            const bool maskit = (kv0 + 63 > qw);

#pragma unroll
            for (int h = 0; h < 2; ++h) {
                const int qh = qw + h * 16 + lr;
                float z[16];
                if (maskit) {
#pragma unroll
                    for (int i = 0; i < 4; ++i)
#pragma unroll
                        for (int j = 0; j < 4; ++j) {
                            int kva = kv0 + i * 16 + g * 4 + j;
                            z[i * 4 + j] = (kva > qh) ? -1e30f : s[h][i][j];
                        }
                } else {
#pragma unroll
                    for (int i = 0; i < 4; ++i)
#pragma unroll
                        for (int j = 0; j < 4; ++j) z[i * 4 + j] = s[h][i][j];
                }

                // row max (raw domain), cross-lane over the 4 g-groups
                float a0 = fmaxf(fmaxf(z[0], z[1]), z[2]);
                float a1 = fmaxf(fmaxf(z[3], z[4]), z[5]);
                float a2 = fmaxf(fmaxf(z[6], z[7]), z[8]);
                float a3 = fmaxf(fmaxf(z[9], z[10]), z[11]);
                float a4 = fmaxf(fmaxf(z[12], z[13]), z[14]);
                float b0 = fmaxf(fmaxf(a0, a1), z[15]);
                float b1 = fmaxf(fmaxf(a2, a3), a4);
                float mt = fmaxf(b0, b1);
                mt = fmaxf(mt, __shfl_xor(mt, 16));
                mt = fmaxf(mt, __shfl_xor(mt, 32));

                const float mnew  = fmaxf(mR[t][h], mt);            // finite always
                const float alpha = exp2f((mnew - mR[t][h]) * -KC); // 1.0 on first
                mR[t][h] = mnew;

                const float mb = -mnew * KC;
                float p[16];
#pragma unroll
                for (int e = 0; e < 16; ++e) p[e] = exp2f(fmaf(z[e], KC, mb)); // masked -> 0

                float psum = ((p[0] + p[1]) + (p[2] + p[3])) + ((p[4] + p[5]) + (p[6] + p[7]))
                           + ((p[8] + p[9]) + (p[10] + p[11])) + ((p[12] + p[13]) + (p[14] + p[15]));
                psum += __shfl_xor(psum, 16);
                psum += __shfl_xor(psum, 32);
                lR[t][h] = lR[t][h] * alpha + psum;

#pragma unroll
                for (int d0 = 0; d0 < 4; ++d0)
#pragma unroll
                    for (int j = 0; j < 4; ++j) oacc[t][h][d0][j] *= alpha;

                union { bf16x8 v; uint32_t w[4]; } pf0, pf1;
#pragma unroll
                for (int w = 0; w < 4; ++w) pf0.w[w] = packbf(p[2 * w], p[2 * w + 1]);
#pragma unroll
                for (int w = 0; w < 4; ++w) pf1.w[w] = packbf(p[8 + 2 * w], p[9 + 2 * w]);

#pragma unroll
                for (int d0 = 0; d0 < 4; ++d0)
                    oacc[t][h][d0] = __builtin_amdgcn_mfma_f32_16x16x32_bf16(vf[0][d0], pf0.v, oacc[t][h][d0], 0, 0, 0);
#pragma unroll
                for (int d0 = 0; d0 < 4; ++d0)
                    oacc[t][h][d0] = __builtin_amdgcn_mfma_f32_16x16x32_bf16(vf[1][d0], pf1.v, oacc[t][h][d0], 0, 0, 0);
            }

#pragma unroll
            for (int i = 0; i < 4; ++i)
#pragma unroll
                for (int dh = 0; dh < 2; ++dh) kc8[i][dh] = kn8[i][dh];
        }
    }

    // ---- serial merge: wave p publishes, wave 0 folds in (p = 1..3) ----
    for (int p = 1; p < 4; ++p) {
        if (wave == p) {
#pragma unroll
            for (int t = 0; t < 2; ++t)
#pragma unroll
                for (int h = 0; h < 2; ++h) {
#pragma unroll
                    for (int d0 = 0; d0 < 4; ++d0)
#pragma unroll
                        for (int j = 0; j < 4; ++j)
                            lds_o[t][h][lane][d0 * 4 + j] = oacc[t][h][d0][j];
                    if (g == 0) {
                        lds_m[t][h][lr] = mR[t][h];
                        lds_l[t][h][lr] = lR[t][h];
                    }
                }
        }
        __syncthreads();
        if (wave == 0) {
#pragma unroll
            for (int t = 0; t < 2; ++t)
#pragma unroll
                for (int h = 0; h < 2; ++h) {
                    const float m1 = lds_m[t][h][lr], l1 = lds_l[t][h][lr];
                    const float mm = fmaxf(mR[t][h], m1);
                    const float w0 = exp2f((mR[t][h] - mm) * KC);
                    const float w1 = exp2f((m1 - mm) * KC);
#pragma unroll
                    for (int d0 = 0; d0 < 4; ++d0)
#pragma unroll
                        for (int j = 0; j < 4; ++j)
                            oacc[t][h][d0][j] = oacc[t][h][d0][j] * w0 + lds_o[t][h][lane][d0 * 4 + j] * w1;
                    lR[t][h] = lR[t][h] * w0 + l1 * w1;
                    mR[t][h] = mm;
                }
        }
        __syncthreads();
    }

    // ---- wave 0 normalizes and stores ----
    if (wave == 0) {
        const int b = bh >> 3, hh = bh & 7;
#pragma unroll
        for (int t = 0; t < 2; ++t) {
            const int qb = (t == 0) ? ord : (127 - ord);
            const int qw = qb * 32;
#pragma unroll
            for (int h = 0; h < 2; ++h) {
                const float inv = 1.0f / lR[t][h];
                unsigned short* orow = attn + ((size_t)(b * T_DIM + qw + h * 16 + lr)) * C_DIM + hh * D_DIM;
#pragma unroll
                for (int d0 = 0; d0 < 4; ++d0) {
                    uint2 st;
                    st.x = packbf(oacc[t][h][d0][0] * inv, oacc[t][h][d0][1] * inv);
                    st.y = packbf(oacc[t][h][d0][2] * inv, oacc[t][h][d0][3] * inv);
                    *(uint2*)(orow + d0 * 16 + g * 4) = st;
                }
            }
        }
    }
}

// ---------- launch ----------
extern "C" void kernel_launch(void* const* d_in, const int* in_sizes, int n_in,
                              void* d_out, int out_size, void* d_ws, size_t ws_size,
                              hipStream_t stream) {
    const float* x  = (const float*)d_in[0];
    const float* Wq = (const float*)d_in[1];
    const float* Wk = (const float*)d_in[2];
    const float* Wv = (const float*)d_in[3];
    const float* Wo = (const float*)d_in[4];

    char* ws = (char*)d_ws;
    // workspace layout (bytes)
    unsigned short* xb    = (unsigned short*)(ws + 0);         //  8 MB  x bf16 [8192][512]
    unsigned short* Wb    = (unsigned short*)(ws + 8388608);   //  2 MB  [4][512][512] bf16
    unsigned short* Qh    = (unsigned short*)(ws + 10485760);  //  8 MB [B][H][T][D]
    unsigned short* Kh    = (unsigned short*)(ws + 18874368);  //  8 MB
    unsigned short* Vt    = (unsigned short*)(ws + 27262976);  //  8 MB [B][H][D][T'] permuted
    unsigned short* attnb = (unsigned short*)(ws + 35651584);  //  8 MB [8192][512]

    const int nX = M_DIM * C_DIM;      // 4194304

    cvt_kernel<<<nX / 4 / 256, 256, 0, stream>>>(x, xb, nX);
    cvt_w_kernel<<<1024, 256, 0, stream>>>(Wq, Wk, Wv, Wo, Wb);

    dim3 gq(M_DIM / 128, C_DIM / 64, 3);
    gemm_qkv<<<gq, 256, 0, stream>>>(xb, Wb, Qh, Kh, Vt);

    attn_kernel<<<B_DIM * H_DIM * (T_DIM / 64), 256, 0, stream>>>(Qh, Kh, Vt, attnb);

    gemm_out<<<dim3(M_DIM / 128, C_DIM / 64), 256, 0, stream>>>(attnb, Wb + 3 * C_DIM * C_DIM, (float*)d_out);
}

// Round 7
// 363.880 us; speedup vs baseline: 1.3961x; 1.3961x over previous
//
#include <hip/hip_runtime.h>
#include <stdint.h>

// ---------- problem constants ----------
#define B_DIM 2
#define T_DIM 4096
#define C_DIM 512
#define H_DIM 8
#define D_DIM 64
#define M_DIM (B_DIM * T_DIM)   // 8192

typedef __attribute__((ext_vector_type(8))) short bf16x8;   // MFMA A/B frag (8 bf16)
typedef __attribute__((ext_vector_type(4))) float f32x4;    // MFMA C/D frag
typedef __attribute__((ext_vector_type(4))) short short4v;  // 8B vector

__device__ inline unsigned short f2bf(float f) {
    union { float f; uint32_t u; } v; v.f = f;
    uint32_t r = v.u + 0x7fffu + ((v.u >> 16) & 1u);   // RNE
    return (unsigned short)(r >> 16);
}

__device__ inline uint32_t packbf(float a, float b) {
    return (uint32_t)f2bf(a) | ((uint32_t)f2bf(b) << 16);
}

// ---------- f32 -> bf16 conversion (x) ----------
__global__ __launch_bounds__(256) void cvt_kernel(const float* __restrict__ in,
                                                  unsigned short* __restrict__ out, int n) {
    int i = (blockIdx.x * 256 + threadIdx.x) * 4;
    if (i >= n) return;
    float4 v = *(const float4*)(in + i);
    short4v o;
    o[0] = (short)f2bf(v.x);
    o[1] = (short)f2bf(v.y);
    o[2] = (short)f2bf(v.z);
    o[3] = (short)f2bf(v.w);
    *(short4v*)(out + i) = o;
}

// ---------- batched f32 -> bf16 for the 4 weight matrices ----------
__global__ __launch_bounds__(256) void cvt_w_kernel(const float* __restrict__ Wq,
                                                    const float* __restrict__ Wk,
                                                    const float* __restrict__ Wv,
                                                    const float* __restrict__ Wo,
                                                    unsigned short* __restrict__ out) {
    const int widx = blockIdx.x >> 8;
    const float* src = (widx == 0) ? Wq : (widx == 1) ? Wk : (widx == 2) ? Wv : Wo;
    const int i = ((blockIdx.x & 255) * 256 + threadIdx.x) * 4;
    float4 v = *(const float4*)(src + i);
    short4v o;
    o[0] = (short)f2bf(v.x);
    o[1] = (short)f2bf(v.y);
    o[2] = (short)f2bf(v.z);
    o[3] = (short)f2bf(v.w);
    *(short4v*)(out + (size_t)widx * C_DIM * C_DIM + i) = o;
}

// ---------- fused Q/K/V GEMM: z = blockIdx.z selects weight & output ----------
// Y[m][n] = sum_k A[m][k] * W[n][k]. 128x64 block tile, wave computes 32x64.
// z=0 -> Q head-split [B][H][T][D]; z=1 -> K same; z=2 -> V transposed+permuted
// [B][H][D][T'] (within each 32-col group column kv at p = ((kv>>2)&3)*8 +
// ((kv>>4)&1)*4 + (kv&3)) so the attn PV A-frag is one contiguous 16B load.
__global__ __launch_bounds__(256) void gemm_qkv(const unsigned short* __restrict__ A,
                                                const unsigned short* __restrict__ Wb,
                                                unsigned short* __restrict__ Qh,
                                                unsigned short* __restrict__ Kh,
                                                unsigned short* __restrict__ Vt) {
    const int wave = threadIdx.x >> 6;
    const int lane = threadIdx.x & 63;
    const int g    = lane >> 4;
    const int lr   = lane & 15;
    const int row0 = blockIdx.x * 128 + wave * 32;
    const int col0 = blockIdx.y * 64;
    const int z    = blockIdx.z;
    const unsigned short* W = Wb + (size_t)z * C_DIM * C_DIM;

    f32x4 acc[2][4];
#pragma unroll
    for (int r = 0; r < 2; ++r)
#pragma unroll
        for (int i = 0; i < 4; ++i) acc[r][i] = (f32x4){0.f, 0.f, 0.f, 0.f};

    const unsigned short* Arow0 = A + (size_t)(row0 + lr) * C_DIM;
    const unsigned short* Arow1 = A + (size_t)(row0 + 16 + lr) * C_DIM;
#pragma unroll 4
    for (int kk = 0; kk < C_DIM; kk += 32) {
        bf16x8 a0 = *(const bf16x8*)(Arow0 + kk + g * 8);
        bf16x8 a1 = *(const bf16x8*)(Arow1 + kk + g * 8);
#pragma unroll
        for (int nt = 0; nt < 4; ++nt) {
            const unsigned short* Wrow = W + (size_t)(col0 + nt * 16 + lr) * C_DIM;
            bf16x8 b = *(const bf16x8*)(Wrow + kk + g * 8);
            acc[0][nt] = __builtin_amdgcn_mfma_f32_16x16x32_bf16(a0, b, acc[0][nt], 0, 0, 0);
            acc[1][nt] = __builtin_amdgcn_mfma_f32_16x16x32_bf16(a1, b, acc[1][nt], 0, 0, 0);
        }
    }

    unsigned short* Oqk = (z == 0) ? Qh : Kh;
#pragma unroll
    for (int ar = 0; ar < 2; ++ar) {
        const int rowb = row0 + ar * 16;
#pragma unroll
        for (int nt = 0; nt < 4; ++nt) {
            const int n = col0 + nt * 16 + lr;
            const int h = n >> 6, d = n & 63;
            if (z < 2) {
#pragma unroll
                for (int j = 0; j < 4; ++j) {
                    int m = rowb + g * 4 + j;
                    int b = m >> 12, t = m & (T_DIM - 1);
                    Oqk[((size_t)(b * H_DIM + h) * T_DIM + t) * D_DIM + d] = f2bf(acc[ar][nt][j]);
                }
            } else {
                int m = rowb + g * 4;
                int b = m >> 12, t = m & (T_DIM - 1);
                int tp = (t & ~31) | (((t >> 2) & 3) << 3) | (((t >> 4) & 1) << 2);
                short4v pack;
#pragma unroll
                for (int j = 0; j < 4; ++j) pack[j] = (short)f2bf(acc[ar][nt][j]);
                *(short4v*)(Vt + ((size_t)(b * H_DIM + h) * D_DIM + d) * T_DIM + tp) = pack;
            }
        }
    }
}

// ---------- output GEMM (f32 out) ----------
__global__ __launch_bounds__(256) void gemm_out(const unsigned short* __restrict__ A,
                                                const unsigned short* __restrict__ W,
                                                float* __restrict__ O) {
    const int wave = threadIdx.x >> 6;
    const int lane = threadIdx.x & 63;
    const int g    = lane >> 4;
    const int lr   = lane & 15;
    const int row0 = blockIdx.x * 128 + wave * 32;
    const int col0 = blockIdx.y * 64;

    f32x4 acc[2][4];
#pragma unroll
    for (int r = 0; r < 2; ++r)
#pragma unroll
        for (int i = 0; i < 4; ++i) acc[r][i] = (f32x4){0.f, 0.f, 0.f, 0.f};

    const unsigned short* Arow0 = A + (size_t)(row0 + lr) * C_DIM;
    const unsigned short* Arow1 = A + (size_t)(row0 + 16 + lr) * C_DIM;
#pragma unroll 4
    for (int kk = 0; kk < C_DIM; kk += 32) {
        bf16x8 a0 = *(const bf16x8*)(Arow0 + kk + g * 8);
        bf16x8 a1 = *(const bf16x8*)(Arow1 + kk + g * 8);
#pragma unroll
        for (int nt = 0; nt < 4; ++nt) {
            const unsigned short* Wrow = W + (size_t)(col0 + nt * 16 + lr) * C_DIM;
            bf16x8 b = *(const bf16x8*)(Wrow + kk + g * 8);
            acc[0][nt] = __builtin_amdgcn_mfma_f32_16x16x32_bf16(a0, b, acc[0][nt], 0, 0, 0);
            acc[1][nt] = __builtin_amdgcn_mfma_f32_16x16x32_bf16(a1, b, acc[1][nt], 0, 0, 0);
        }
    }

#pragma unroll
    for (int ar = 0; ar < 2; ++ar) {
        const int rowb = row0 + ar * 16;
#pragma unroll
        for (int nt = 0; nt < 4; ++nt) {
            const int n = col0 + nt * 16 + lr;
#pragma unroll
            for (int j = 0; j < 4; ++j) {
                int m = rowb + g * 4 + j;
                O[(size_t)m * C_DIM + n] = acc[ar][nt][j];
            }
        }
    }
}

// ---------- causal flash attention, 4-way parity split, ONE tile live ----------
// Q,K: [B*H][T][D] bf16.  Vt: [B*H][D][T'] bf16 (kv-permuted).  attn out: [B*T][C] bf16.
// Block = 256 threads = 4 waves; owns tile pair (qb=ord, 127-ord) of one head,
// processed SEQUENTIALLY (one tile's state live at a time -> ~112 live VGPRs,
// fits the 128-reg cap of 16 waves/CU; round-6 spilled by keeping both).
// Within a tile, wave w handles kv0 = w*64 + 256k. No K prefetch: 4 waves/SIMD
// of TLP hide load latency instead of ILP. Merge: waves 1-3 publish partials to
// 3 LDS slots, one barrier, wave 0 folds + stores (2 barriers per tile).
// All softmax arithmetic finite (sentinel/mask -1e30): empty wave -> weight 0.
__global__ __launch_bounds__(256, 4) void attn_kernel(const unsigned short* __restrict__ Qh,
                                                      const unsigned short* __restrict__ Kh,
                                                      const unsigned short* __restrict__ Vt,
                                                      unsigned short* __restrict__ attn) {
    const int wave = threadIdx.x >> 6;   // kv parity 0..3
    const int lane = threadIdx.x & 63;
    const int g    = lane >> 4;
    const int lr   = lane & 15;
    const int bh   = blockIdx.x & 15;    // head in low bits -> per-XCD K/V locality
    const int ord  = blockIdx.x >> 4;    // 0..63

    const unsigned short* Qp = Qh + (size_t)bh * T_DIM * D_DIM;
    const unsigned short* Kp = Kh + (size_t)bh * T_DIM * D_DIM;
    const unsigned short* Vp = Vt + (size_t)bh * D_DIM * T_DIM;

    const float KC = 0.125f * 1.44269504f;   // scale * log2(e)

    __shared__ float lds_o[3][2][64][17];    // [slot][h][lane][16 elems + pad]
    __shared__ float lds_m[3][2][16];
    __shared__ float lds_l[3][2][16];

#pragma unroll 1
    for (int t = 0; t < 2; ++t) {
        const int qb = t ? (127 - ord) : ord;
        const int qw = qb * 32;
        const int kvend = qw + 32;

        bf16x8 qf[2][2];
#pragma unroll
        for (int h = 0; h < 2; ++h)
#pragma unroll
            for (int dh = 0; dh < 2; ++dh)
                qf[h][dh] = *(const bf16x8*)(Qp + (size_t)(qw + h * 16 + lr) * D_DIM + dh * 32 + g * 8);

        f32x4 oacc[2][4];
        float mR[2], lR[2];
#pragma unroll
        for (int h = 0; h < 2; ++h) {
#pragma unroll
            for (int d0 = 0; d0 < 4; ++d0) oacc[h][d0] = (f32x4){0.f, 0.f, 0.f, 0.f};
            mR[h] = -1e30f;
            lR[h] = 0.f;
        }

#pragma unroll 1
        for (int kv0 = wave * 64; kv0 < kvend; kv0 += 256) {
            // ---- K frags (8 x 16B, issued first) ----
            bf16x8 kc8[4][2];
#pragma unroll
            for (int i = 0; i < 4; ++i)
#pragma unroll
                for (int dh = 0; dh < 2; ++dh)
                    kc8[i][dh] = *(const bf16x8*)(Kp + (size_t)(kv0 + i * 16 + lr) * D_DIM + dh * 32 + g * 8);

            // ---- V frags (8 x 16B, independent, in flight during QK^T) ----
            bf16x8 vf[2][4];
#pragma unroll
            for (int kh = 0; kh < 2; ++kh)
#pragma unroll
                for (int d0 = 0; d0 < 4; ++d0)
                    vf[kh][d0] = *(const bf16x8*)(Vp + (size_t)(d0 * 16 + lr) * T_DIM + kv0 + kh * 32 + g * 8);

            // ---- QK^T: both q-halves share every K frag ----
            f32x4 s[2][4];
#pragma unroll
            for (int h = 0; h < 2; ++h)
#pragma unroll
                for (int i = 0; i < 4; ++i) s[h][i] = (f32x4){0.f, 0.f, 0.f, 0.f};
#pragma unroll
            for (int i = 0; i < 4; ++i) {
                s[0][i] = __builtin_amdgcn_mfma_f32_16x16x32_bf16(kc8[i][0], qf[0][0], s[0][i], 0, 0, 0);
                s[0][i] = __builtin_amdgcn_mfma_f32_16x16x32_bf16(kc8[i][1], qf[0][1], s[0][i], 0, 0, 0);
                s[1][i] = __builtin_amdgcn_mfma_f32_16x16x32_bf16(kc8[i][0], qf[1][0], s[1][i], 0, 0, 0);
                s[1][i] = __builtin_amdgcn_mfma_f32_16x16x32_bf16(kc8[i][1], qf[1][1], s[1][i], 0, 0, 0);
            }

            const bool maskit = (kv0 + 63 > qw);

#pragma unroll
            for (int h = 0; h < 2; ++h) {
                const int qh = qw + h * 16 + lr;
                float z[16];
                if (maskit) {
#pragma unroll
                    for (int i = 0; i < 4; ++i)
#pragma unroll
                        for (int j = 0; j < 4; ++j) {
                            int kva = kv0 + i * 16 + g * 4 + j;
                            z[i * 4 + j] = (kva > qh) ? -1e30f : s[h][i][j];
                        }
                } else {
#pragma unroll
                    for (int i = 0; i < 4; ++i)
#pragma unroll
                        for (int j = 0; j < 4; ++j) z[i * 4 + j] = s[h][i][j];
                }

                float a0 = fmaxf(fmaxf(z[0], z[1]), z[2]);
                float a1 = fmaxf(fmaxf(z[3], z[4]), z[5]);
                float a2 = fmaxf(fmaxf(z[6], z[7]), z[8]);
                float a3 = fmaxf(fmaxf(z[9], z[10]), z[11]);
                float a4 = fmaxf(fmaxf(z[12], z[13]), z[14]);
                float b0 = fmaxf(fmaxf(a0, a1), z[15]);
                float b1 = fmaxf(fmaxf(a2, a3), a4);
                float mt = fmaxf(b0, b1);
                mt = fmaxf(mt, __shfl_xor(mt, 16));
                mt = fmaxf(mt, __shfl_xor(mt, 32));

                const float mnew  = fmaxf(mR[h], mt);
                const float alpha = exp2f((mnew - mR[h]) * -KC);  // 1.0 on first iter
                mR[h] = mnew;

                const float mb = -mnew * KC;
                float p[16];
#pragma unroll
                for (int e = 0; e < 16; ++e) p[e] = exp2f(fmaf(z[e], KC, mb)); // masked -> 0

                float psum = ((p[0] + p[1]) + (p[2] + p[3])) + ((p[4] + p[5]) + (p[6] + p[7]))
                           + ((p[8] + p[9]) + (p[10] + p[11])) + ((p[12] + p[13]) + (p[14] + p[15]));
                psum += __shfl_xor(psum, 16);
                psum += __shfl_xor(psum, 32);
                lR[h] = lR[h] * alpha + psum;

#pragma unroll
                for (int d0 = 0; d0 < 4; ++d0)
#pragma unroll
                    for (int j = 0; j < 4; ++j) oacc[h][d0][j] *= alpha;

                union { bf16x8 v; uint32_t w[4]; } pf0, pf1;
#pragma unroll
                for (int w = 0; w < 4; ++w) pf0.w[w] = packbf(p[2 * w], p[2 * w + 1]);
#pragma unroll
                for (int w = 0; w < 4; ++w) pf1.w[w] = packbf(p[8 + 2 * w], p[9 + 2 * w]);

#pragma unroll
                for (int d0 = 0; d0 < 4; ++d0)
                    oacc[h][d0] = __builtin_amdgcn_mfma_f32_16x16x32_bf16(vf[0][d0], pf0.v, oacc[h][d0], 0, 0, 0);
#pragma unroll
                for (int d0 = 0; d0 < 4; ++d0)
                    oacc[h][d0] = __builtin_amdgcn_mfma_f32_16x16x32_bf16(vf[1][d0], pf1.v, oacc[h][d0], 0, 0, 0);
            }
        }

        // ---- waves 1..3 publish partials to their slot ----
        if (wave > 0) {
            const int slot = wave - 1;
#pragma unroll
            for (int h = 0; h < 2; ++h) {
#pragma unroll
                for (int d0 = 0; d0 < 4; ++d0)
#pragma unroll
                    for (int j = 0; j < 4; ++j)
                        lds_o[slot][h][lane][d0 * 4 + j] = oacc[h][d0][j];
                if (g == 0) {
                    lds_m[slot][h][lr] = mR[h];
                    lds_l[slot][h][lr] = lR[h];
                }
            }
        }
        __syncthreads();

        // ---- wave 0 folds the 3 slots, normalizes, stores ----
        if (wave == 0) {
#pragma unroll
            for (int slot = 0; slot < 3; ++slot)
#pragma unroll
                for (int h = 0; h < 2; ++h) {
                    const float m1 = lds_m[slot][h][lr], l1 = lds_l[slot][h][lr];
                    const float mm = fmaxf(mR[h], m1);
                    const float w0 = exp2f((mR[h] - mm) * KC);
                    const float w1 = exp2f((m1 - mm) * KC);
#pragma unroll
                    for (int d0 = 0; d0 < 4; ++d0)
#pragma unroll
                        for (int j = 0; j < 4; ++j)
                            oacc[h][d0][j] = oacc[h][d0][j] * w0 + lds_o[slot][h][lane][d0 * 4 + j] * w1;
                    lR[h] = lR[h] * w0 + l1 * w1;
                    mR[h] = mm;
                }

            const int b = bh >> 3, hh = bh & 7;
#pragma unroll
            for (int h = 0; h < 2; ++h) {
                const float inv = 1.0f / lR[h];
                unsigned short* orow = attn + ((size_t)(b * T_DIM + qw + h * 16 + lr)) * C_DIM + hh * D_DIM;
#pragma unroll
                for (int d0 = 0; d0 < 4; ++d0) {
                    uint2 st;
                    st.x = packbf(oacc[h][d0][0] * inv, oacc[h][d0][1] * inv);
                    st.y = packbf(oacc[h][d0][2] * inv, oacc[h][d0][3] * inv);
                    *(uint2*)(orow + d0 * 16 + g * 4) = st;
                }
            }
        }
        __syncthreads();   // LDS reuse safety before next tile
    }
}

// ---------- launch ----------
extern "C" void kernel_launch(void* const* d_in, const int* in_sizes, int n_in,
                              void* d_out, int out_size, void* d_ws, size_t ws_size,
                              hipStream_t stream) {
    const float* x  = (const float*)d_in[0];
    const float* Wq = (const float*)d_in[1];
    const float* Wk = (const float*)d_in[2];
    const float* Wv = (const float*)d_in[3];
    const float* Wo = (const float*)d_in[4];

    char* ws = (char*)d_ws;
    unsigned short* xb    = (unsigned short*)(ws + 0);         //  8 MB  x bf16 [8192][512]
    unsigned short* Wb    = (unsigned short*)(ws + 8388608);   //  2 MB  [4][512][512] bf16
    unsigned short* Qh    = (unsigned short*)(ws + 10485760);  //  8 MB [B][H][T][D]
    unsigned short* Kh    = (unsigned short*)(ws + 18874368);  //  8 MB
    unsigned short* Vt    = (unsigned short*)(ws + 27262976);  //  8 MB [B][H][D][T'] permuted
    unsigned short* attnb = (unsigned short*)(ws + 35651584);  //  8 MB [8192][512]

    const int nX = M_DIM * C_DIM;      // 4194304

    cvt_kernel<<<nX / 4 / 256, 256, 0, stream>>>(x, xb, nX);
    cvt_w_kernel<<<1024, 256, 0, stream>>>(Wq, Wk, Wv, Wo, Wb);

    dim3 gq(M_DIM / 128, C_DIM / 64, 3);
    gemm_qkv<<<gq, 256, 0, stream>>>(xb, Wb, Qh, Kh, Vt);

    attn_kernel<<<B_DIM * H_DIM * (T_DIM / 64), 256, 0, stream>>>(Qh, Kh, Vt, attnb);

    gemm_out<<<dim3(M_DIM / 128, C_DIM / 64), 256, 0, stream>>>(attnb, Wb + 3 * C_DIM * C_DIM, (float*)d_out);
}

// Round 8
// 266.770 us; speedup vs baseline: 1.9043x; 1.3640x over previous
//
#include <hip/hip_runtime.h>
#include <stdint.h>

// ---------- problem constants ----------
#define B_DIM 2
#define T_DIM 4096
#define C_DIM 512
#define H_DIM 8
#define D_DIM 64
#define M_DIM (B_DIM * T_DIM)   // 8192

typedef __attribute__((ext_vector_type(8))) short bf16x8;   // MFMA A/B frag (8 bf16)
typedef __attribute__((ext_vector_type(4))) float f32x4;    // MFMA C/D frag
typedef __attribute__((ext_vector_type(4))) short short4v;  // 8B vector

__device__ inline unsigned short f2bf(float f) {
    union { float f; uint32_t u; } v; v.f = f;
    uint32_t r = v.u + 0x7fffu + ((v.u >> 16) & 1u);   // RNE
    return (unsigned short)(r >> 16);
}

__device__ inline uint32_t packbf(float a, float b) {
    return (uint32_t)f2bf(a) | ((uint32_t)f2bf(b) << 16);
}

// ---------- f32 -> bf16 conversion (x) ----------
__global__ __launch_bounds__(256) void cvt_kernel(const float* __restrict__ in,
                                                  unsigned short* __restrict__ out, int n) {
    int i = (blockIdx.x * 256 + threadIdx.x) * 4;
    if (i >= n) return;
    float4 v = *(const float4*)(in + i);
    short4v o;
    o[0] = (short)f2bf(v.x);
    o[1] = (short)f2bf(v.y);
    o[2] = (short)f2bf(v.z);
    o[3] = (short)f2bf(v.w);
    *(short4v*)(out + i) = o;
}

// ---------- batched f32 -> bf16 for the 4 weight matrices ----------
__global__ __launch_bounds__(256) void cvt_w_kernel(const float* __restrict__ Wq,
                                                    const float* __restrict__ Wk,
                                                    const float* __restrict__ Wv,
                                                    const float* __restrict__ Wo,
                                                    unsigned short* __restrict__ out) {
    const int widx = blockIdx.x >> 8;
    const float* src = (widx == 0) ? Wq : (widx == 1) ? Wk : (widx == 2) ? Wv : Wo;
    const int i = ((blockIdx.x & 255) * 256 + threadIdx.x) * 4;
    float4 v = *(const float4*)(src + i);
    short4v o;
    o[0] = (short)f2bf(v.x);
    o[1] = (short)f2bf(v.y);
    o[2] = (short)f2bf(v.z);
    o[3] = (short)f2bf(v.w);
    *(short4v*)(out + (size_t)widx * C_DIM * C_DIM + i) = o;
}

// ---------- fused Q/K/V GEMM: z = blockIdx.z selects weight & output ----------
// Y[m][n] = sum_k A[m][k] * W[n][k]. 128x64 block tile, wave computes 32x64.
// z=0 -> Q head-split [B][H][T][D]; z=1 -> K same; z=2 -> V transposed+permuted
// [B][H][D][T'] (within each 32-col group column kv at p = ((kv>>2)&3)*8 +
// ((kv>>4)&1)*4 + (kv&3)) so the attn PV A-frag is one contiguous 16B load.
__global__ __launch_bounds__(256) void gemm_qkv(const unsigned short* __restrict__ A,
                                                const unsigned short* __restrict__ Wb,
                                                unsigned short* __restrict__ Qh,
                                                unsigned short* __restrict__ Kh,
                                                unsigned short* __restrict__ Vt) {
    const int wave = threadIdx.x >> 6;
    const int lane = threadIdx.x & 63;
    const int g    = lane >> 4;
    const int lr   = lane & 15;
    const int row0 = blockIdx.x * 128 + wave * 32;
    const int col0 = blockIdx.y * 64;
    const int z    = blockIdx.z;
    const unsigned short* W = Wb + (size_t)z * C_DIM * C_DIM;

    f32x4 acc[2][4];
#pragma unroll
    for (int r = 0; r < 2; ++r)
#pragma unroll
        for (int i = 0; i < 4; ++i) acc[r][i] = (f32x4){0.f, 0.f, 0.f, 0.f};

    const unsigned short* Arow0 = A + (size_t)(row0 + lr) * C_DIM;
    const unsigned short* Arow1 = A + (size_t)(row0 + 16 + lr) * C_DIM;
#pragma unroll 4
    for (int kk = 0; kk < C_DIM; kk += 32) {
        bf16x8 a0 = *(const bf16x8*)(Arow0 + kk + g * 8);
        bf16x8 a1 = *(const bf16x8*)(Arow1 + kk + g * 8);
#pragma unroll
        for (int nt = 0; nt < 4; ++nt) {
            const unsigned short* Wrow = W + (size_t)(col0 + nt * 16 + lr) * C_DIM;
            bf16x8 b = *(const bf16x8*)(Wrow + kk + g * 8);
            acc[0][nt] = __builtin_amdgcn_mfma_f32_16x16x32_bf16(a0, b, acc[0][nt], 0, 0, 0);
            acc[1][nt] = __builtin_amdgcn_mfma_f32_16x16x32_bf16(a1, b, acc[1][nt], 0, 0, 0);
        }
    }

    unsigned short* Oqk = (z == 0) ? Qh : Kh;
#pragma unroll
    for (int ar = 0; ar < 2; ++ar) {
        const int rowb = row0 + ar * 16;
#pragma unroll
        for (int nt = 0; nt < 4; ++nt) {
            const int n = col0 + nt * 16 + lr;
            const int h = n >> 6, d = n & 63;
            if (z < 2) {
#pragma unroll
                for (int j = 0; j < 4; ++j) {
                    int m = rowb + g * 4 + j;
                    int b = m >> 12, t = m & (T_DIM - 1);
                    Oqk[((size_t)(b * H_DIM + h) * T_DIM + t) * D_DIM + d] = f2bf(acc[ar][nt][j]);
                }
            } else {
                int m = rowb + g * 4;
                int b = m >> 12, t = m & (T_DIM - 1);
                int tp = (t & ~31) | (((t >> 2) & 3) << 3) | (((t >> 4) & 1) << 2);
                short4v pack;
#pragma unroll
                for (int j = 0; j < 4; ++j) pack[j] = (short)f2bf(acc[ar][nt][j]);
                *(short4v*)(Vt + ((size_t)(b * H_DIM + h) * D_DIM + d) * T_DIM + tp) = pack;
            }
        }
    }
}

// ---------- output GEMM (f32 out) ----------
__global__ __launch_bounds__(256) void gemm_out(const unsigned short* __restrict__ A,
                                                const unsigned short* __restrict__ W,
                                                float* __restrict__ O) {
    const int wave = threadIdx.x >> 6;
    const int lane = threadIdx.x & 63;
    const int g    = lane >> 4;
    const int lr   = lane & 15;
    const int row0 = blockIdx.x * 128 + wave * 32;
    const int col0 = blockIdx.y * 64;

    f32x4 acc[2][4];
#pragma unroll
    for (int r = 0; r < 2; ++r)
#pragma unroll
        for (int i = 0; i < 4; ++i) acc[r][i] = (f32x4){0.f, 0.f, 0.f, 0.f};

    const unsigned short* Arow0 = A + (size_t)(row0 + lr) * C_DIM;
    const unsigned short* Arow1 = A + (size_t)(row0 + 16 + lr) * C_DIM;
#pragma unroll 4
    for (int kk = 0; kk < C_DIM; kk += 32) {
        bf16x8 a0 = *(const bf16x8*)(Arow0 + kk + g * 8);
        bf16x8 a1 = *(const bf16x8*)(Arow1 + kk + g * 8);
#pragma unroll
        for (int nt = 0; nt < 4; ++nt) {
            const unsigned short* Wrow = W + (size_t)(col0 + nt * 16 + lr) * C_DIM;
            bf16x8 b = *(const bf16x8*)(Wrow + kk + g * 8);
            acc[0][nt] = __builtin_amdgcn_mfma_f32_16x16x32_bf16(a0, b, acc[0][nt], 0, 0, 0);
            acc[1][nt] = __builtin_amdgcn_mfma_f32_16x16x32_bf16(a1, b, acc[1][nt], 0, 0, 0);
        }
    }

#pragma unroll
    for (int ar = 0; ar < 2; ++ar) {
        const int rowb = row0 + ar * 16;
#pragma unroll
        for (int nt = 0; nt < 4; ++nt) {
            const int n = col0 + nt * 16 + lr;
#pragma unroll
            for (int j = 0; j < 4; ++j) {
                int m = rowb + g * 4 + j;
                O[(size_t)m * C_DIM + n] = acc[ar][nt][j];
            }
        }
    }
}

// ---------- causal flash attention: 3 waves/block, 3-way kv parity ----------
// Q,K: [B*H][T][D] bf16.  Vt: [B*H][D][T'] bf16 (kv-permuted).  attn out: [B*T][C] bf16.
// Block = 192 threads = 3 waves; owns tile pair (qb=ord, 127-ord) of one head,
// tiles processed SEQUENTIALLY (one tile's state live -> ~140 live regs).
// __launch_bounds__(192,3): VGPR cap 170 >= live state -> NO SPILL (r6/r7 lesson:
// demanding 4 waves/SIMD caps at 128 and spills catastrophically). 1024 uniform
// blocks = 4 blocks/CU = 12 waves/CU = 3 waves/SIMD exactly, zero tail.
// Wave w handles kv0 = w*64 + 192k. V loaded in halves (vf0 pre-QK^T, vf1 post)
// to trim peak pressure. Waves 1-2 publish partials to LDS; wave 0 folds+stores.
// All softmax arithmetic finite (sentinel/mask -1e30): empty wave -> weight 0.
__global__ __launch_bounds__(192, 3) void attn_kernel(const unsigned short* __restrict__ Qh,
                                                      const unsigned short* __restrict__ Kh,
                                                      const unsigned short* __restrict__ Vt,
                                                      unsigned short* __restrict__ attn) {
    const int wave = threadIdx.x >> 6;   // kv parity 0..2
    const int lane = threadIdx.x & 63;
    const int g    = lane >> 4;
    const int lr   = lane & 15;
    const int bh   = blockIdx.x & 15;    // head in low bits -> L2 K/V locality
    const int ord  = blockIdx.x >> 4;    // 0..63

    const unsigned short* Qp = Qh + (size_t)bh * T_DIM * D_DIM;
    const unsigned short* Kp = Kh + (size_t)bh * T_DIM * D_DIM;
    const unsigned short* Vp = Vt + (size_t)bh * D_DIM * T_DIM;

    const float KC = 0.125f * 1.44269504f;   // scale * log2(e)

    __shared__ float lds_o[2][2][64][17];    // [slot][h][lane][16 elems + pad]
    __shared__ float lds_m[2][2][16];
    __shared__ float lds_l[2][2][16];

#pragma unroll 1
    for (int t = 0; t < 2; ++t) {
        const int qb = t ? (127 - ord) : ord;
        const int qw = qb * 32;
        const int kvend = qw + 32;

        bf16x8 qf[2][2];
#pragma unroll
        for (int h = 0; h < 2; ++h)
#pragma unroll
            for (int dh = 0; dh < 2; ++dh)
                qf[h][dh] = *(const bf16x8*)(Qp + (size_t)(qw + h * 16 + lr) * D_DIM + dh * 32 + g * 8);

        f32x4 oacc[2][4];
        float mR[2], lR[2];
#pragma unroll
        for (int h = 0; h < 2; ++h) {
#pragma unroll
            for (int d0 = 0; d0 < 4; ++d0) oacc[h][d0] = (f32x4){0.f, 0.f, 0.f, 0.f};
            mR[h] = -1e30f;
            lR[h] = 0.f;
        }

#pragma unroll 1
        for (int kv0 = wave * 64; kv0 < kvend; kv0 += 192) {
            // ---- K frags (8 x 16B) ----
            bf16x8 kc8[4][2];
#pragma unroll
            for (int i = 0; i < 4; ++i)
#pragma unroll
                for (int dh = 0; dh < 2; ++dh)
                    kc8[i][dh] = *(const bf16x8*)(Kp + (size_t)(kv0 + i * 16 + lr) * D_DIM + dh * 32 + g * 8);

            // ---- V first half (4 x 16B, in flight during QK^T) ----
            bf16x8 vf0[4];
#pragma unroll
            for (int d0 = 0; d0 < 4; ++d0)
                vf0[d0] = *(const bf16x8*)(Vp + (size_t)(d0 * 16 + lr) * T_DIM + kv0 + g * 8);

            // ---- QK^T: both q-halves share every K frag ----
            f32x4 s[2][4];
#pragma unroll
            for (int h = 0; h < 2; ++h)
#pragma unroll
                for (int i = 0; i < 4; ++i) s[h][i] = (f32x4){0.f, 0.f, 0.f, 0.f};
#pragma unroll
            for (int i = 0; i < 4; ++i) {
                s[0][i] = __builtin_amdgcn_mfma_f32_16x16x32_bf16(kc8[i][0], qf[0][0], s[0][i], 0, 0, 0);
                s[0][i] = __builtin_amdgcn_mfma_f32_16x16x32_bf16(kc8[i][1], qf[0][1], s[0][i], 0, 0, 0);
                s[1][i] = __builtin_amdgcn_mfma_f32_16x16x32_bf16(kc8[i][0], qf[1][0], s[1][i], 0, 0, 0);
                s[1][i] = __builtin_amdgcn_mfma_f32_16x16x32_bf16(kc8[i][1], qf[1][1], s[1][i], 0, 0, 0);
            }

            // ---- V second half (in flight during softmax) ----
            bf16x8 vf1[4];
#pragma unroll
            for (int d0 = 0; d0 < 4; ++d0)
                vf1[d0] = *(const bf16x8*)(Vp + (size_t)(d0 * 16 + lr) * T_DIM + kv0 + 32 + g * 8);

            const bool maskit = (kv0 + 63 > qw);

#pragma unroll
            for (int h = 0; h < 2; ++h) {
                const int qh = qw + h * 16 + lr;
                float z[16];
                if (maskit) {
#pragma unroll
                    for (int i = 0; i < 4; ++i)
#pragma unroll
                        for (int j = 0; j < 4; ++j) {
                            int kva = kv0 + i * 16 + g * 4 + j;
                            z[i * 4 + j] = (kva > qh) ? -1e30f : s[h][i][j];
                        }
                } else {
#pragma unroll
                    for (int i = 0; i < 4; ++i)
#pragma unroll
                        for (int j = 0; j < 4; ++j) z[i * 4 + j] = s[h][i][j];
                }

                float a0 = fmaxf(fmaxf(z[0], z[1]), z[2]);
                float a1 = fmaxf(fmaxf(z[3], z[4]), z[5]);
                float a2 = fmaxf(fmaxf(z[6], z[7]), z[8]);
                float a3 = fmaxf(fmaxf(z[9], z[10]), z[11]);
                float a4 = fmaxf(fmaxf(z[12], z[13]), z[14]);
                float b0 = fmaxf(fmaxf(a0, a1), z[15]);
                float b1 = fmaxf(fmaxf(a2, a3), a4);
                float mt = fmaxf(b0, b1);
                mt = fmaxf(mt, __shfl_xor(mt, 16));
                mt = fmaxf(mt, __shfl_xor(mt, 32));

                const float mnew  = fmaxf(mR[h], mt);
                const float alpha = exp2f((mnew - mR[h]) * -KC);  // 1.0 on first iter
                mR[h] = mnew;

                const float mb = -mnew * KC;
                float p[16];
#pragma unroll
                for (int e = 0; e < 16; ++e) p[e] = exp2f(fmaf(z[e], KC, mb)); // masked -> 0

                float psum = ((p[0] + p[1]) + (p[2] + p[3])) + ((p[4] + p[5]) + (p[6] + p[7]))
                           + ((p[8] + p[9]) + (p[10] + p[11])) + ((p[12] + p[13]) + (p[14] + p[15]));
                psum += __shfl_xor(psum, 16);
                psum += __shfl_xor(psum, 32);
                lR[h] = lR[h] * alpha + psum;

#pragma unroll
                for (int d0 = 0; d0 < 4; ++d0)
#pragma unroll
                    for (int j = 0; j < 4; ++j) oacc[h][d0][j] *= alpha;

                union { bf16x8 v; uint32_t w[4]; } pf0, pf1;
#pragma unroll
                for (int w = 0; w < 4; ++w) pf0.w[w] = packbf(p[2 * w], p[2 * w + 1]);
#pragma unroll
                for (int w = 0; w < 4; ++w) pf1.w[w] = packbf(p[8 + 2 * w], p[9 + 2 * w]);

#pragma unroll
                for (int d0 = 0; d0 < 4; ++d0)
                    oacc[h][d0] = __builtin_amdgcn_mfma_f32_16x16x32_bf16(vf0[d0], pf0.v, oacc[h][d0], 0, 0, 0);
#pragma unroll
                for (int d0 = 0; d0 < 4; ++d0)
                    oacc[h][d0] = __builtin_amdgcn_mfma_f32_16x16x32_bf16(vf1[d0], pf1.v, oacc[h][d0], 0, 0, 0);
            }
        }

        // ---- waves 1..2 publish partials to their slot ----
        if (wave > 0) {
            const int slot = wave - 1;
#pragma unroll
            for (int h = 0; h < 2; ++h) {
#pragma unroll
                for (int d0 = 0; d0 < 4; ++d0)
#pragma unroll
                    for (int j = 0; j < 4; ++j)
                        lds_o[slot][h][lane][d0 * 4 + j] = oacc[h][d0][j];
                if (g == 0) {
                    lds_m[slot][h][lr] = mR[h];
                    lds_l[slot][h][lr] = lR[h];
                }
            }
        }
        __syncthreads();

        // ---- wave 0 folds the 2 slots, normalizes, stores ----
        if (wave == 0) {
#pragma unroll
            for (int slot = 0; slot < 2; ++slot)
#pragma unroll
                for (int h = 0; h < 2; ++h) {
                    const float m1 = lds_m[slot][h][lr], l1 = lds_l[slot][h][lr];
                    const float mm = fmaxf(mR[h], m1);
                    const float w0 = exp2f((mR[h] - mm) * KC);
                    const float w1 = exp2f((m1 - mm) * KC);
#pragma unroll
                    for (int d0 = 0; d0 < 4; ++d0)
#pragma unroll
                        for (int j = 0; j < 4; ++j)
                            oacc[h][d0][j] = oacc[h][d0][j] * w0 + lds_o[slot][h][lane][d0 * 4 + j] * w1;
                    lR[h] = lR[h] * w0 + l1 * w1;
                    mR[h] = mm;
                }

            const int b = bh >> 3, hh = bh & 7;
#pragma unroll
            for (int h = 0; h < 2; ++h) {
                const float inv = 1.0f / lR[h];
                unsigned short* orow = attn + ((size_t)(b * T_DIM + qw + h * 16 + lr)) * C_DIM + hh * D_DIM;
#pragma unroll
                for (int d0 = 0; d0 < 4; ++d0) {
                    uint2 st;
                    st.x = packbf(oacc[h][d0][0] * inv, oacc[h][d0][1] * inv);
                    st.y = packbf(oacc[h][d0][2] * inv, oacc[h][d0][3] * inv);
                    *(uint2*)(orow + d0 * 16 + g * 4) = st;
                }
            }
        }
        __syncthreads();   // LDS reuse safety before next tile
    }
}

// ---------- launch ----------
extern "C" void kernel_launch(void* const* d_in, const int* in_sizes, int n_in,
                              void* d_out, int out_size, void* d_ws, size_t ws_size,
                              hipStream_t stream) {
    const float* x  = (const float*)d_in[0];
    const float* Wq = (const float*)d_in[1];
    const float* Wk = (const float*)d_in[2];
    const float* Wv = (const float*)d_in[3];
    const float* Wo = (const float*)d_in[4];

    char* ws = (char*)d_ws;
    unsigned short* xb    = (unsigned short*)(ws + 0);         //  8 MB  x bf16 [8192][512]
    unsigned short* Wb    = (unsigned short*)(ws + 8388608);   //  2 MB  [4][512][512] bf16
    unsigned short* Qh    = (unsigned short*)(ws + 10485760);  //  8 MB [B][H][T][D]
    unsigned short* Kh    = (unsigned short*)(ws + 18874368);  //  8 MB
    unsigned short* Vt    = (unsigned short*)(ws + 27262976);  //  8 MB [B][H][D][T'] permuted
    unsigned short* attnb = (unsigned short*)(ws + 35651584);  //  8 MB [8192][512]

    const int nX = M_DIM * C_DIM;      // 4194304

    cvt_kernel<<<nX / 4 / 256, 256, 0, stream>>>(x, xb, nX);
    cvt_w_kernel<<<1024, 256, 0, stream>>>(Wq, Wk, Wv, Wo, Wb);

    dim3 gq(M_DIM / 128, C_DIM / 64, 3);
    gemm_qkv<<<gq, 256, 0, stream>>>(xb, Wb, Qh, Kh, Vt);

    attn_kernel<<<B_DIM * H_DIM * (T_DIM / 64), 192, 0, stream>>>(Qh, Kh, Vt, attnb);

    gemm_out<<<dim3(M_DIM / 128, C_DIM / 64), 256, 0, stream>>>(attnb, Wb + 3 * C_DIM * C_DIM, (float*)d_out);
}